// Round 1
// baseline (1105.856 us; speedup 1.0000x reference)
//
#include <hip/hip_runtime.h>
#include <stdint.h>
#include <math.h>

#define T_TOK 512
#define DDIM  2048
#define IDIM  768
#define NEXP  16
#define TOPK  8

// ---------- fp8 e4m3fn round-to-nearest-even quant-dequant helpers ----------
__device__ __forceinline__ float e4m3_rtne(float f) {
  // |f| <= 448 guaranteed by construction (amax/rscale <= 448)
  uint32_t u = __float_as_uint(f);
  uint32_t sign = u & 0x80000000u;
  uint32_t a = u & 0x7FFFFFFFu;
  float fa = __uint_as_float(a);
  float out;
  if (fa >= 0.015625f) {            // normal e4m3 range: keep 3 mantissa bits, RTNE
    uint32_t lsb = (a >> 20) & 1u;
    a += 0x0007FFFFu + lsb;
    a &= 0xFFF00000u;
    out = __uint_as_float(a);
  } else {                          // subnormal range: quantum 2^-9
    out = rintf(fa * 512.0f) * 0.001953125f;
  }
  return __uint_as_float(__float_as_uint(out) | sign);
}

__global__ void qdq_kernel(const float* __restrict__ x, float* __restrict__ xq) {
  int idx = blockIdx.x * 256 + threadIdx.x;
  float v = x[idx];
  float a = fabsf(v);
#pragma unroll
  for (int m = 16; m >= 1; m >>= 1)
    a = fmaxf(a, __shfl_xor(a, m, 32));   // group of 32 = one scale group
  a = fmaxf(a, 1e-4f);
  float scale = a / 448.0f;
  uint32_t b = __float_as_uint(scale);
  uint32_t ex = ((b >> 23) & 255u) + ((b & 0x7FFFFFu) ? 1u : 0u);  // round exp up
  ex = ex < 1u ? 1u : (ex > 254u ? 254u : ex);
  float rscale = __uint_as_float(ex << 23);
  float inv = 1.0f / rscale;              // exact (power of 2)
  xq[idx] = e4m3_rtne(v * inv) * rscale;
}

// ---------- routing: per-expert token lists, comb weights, offsets ----------
__global__ void route_kernel(const int* __restrict__ ids, const float* __restrict__ wts,
                             int* counts, int* offsets, int* lists, float* combs) {
  int t = threadIdx.x;  // 512 threads
  int  myid[TOPK];
  float myw[TOPK];
#pragma unroll
  for (int k = 0; k < TOPK; k++) { myid[k] = ids[t*TOPK+k]; myw[k] = wts[t*TOPK+k]; }
  for (int e = 0; e < NEXP; e++) {
    float s = 0.f; bool r = false;
#pragma unroll
    for (int k = 0; k < TOPK; k++) if (myid[k] == e) { s += myw[k]; r = true; }
    if (r) {
      int slot = atomicAdd(&counts[e], 1);
      lists[(e<<9) + slot] = t;
      combs[(e<<9) + slot] = s;
    }
  }
  __syncthreads();
  if (t == 0) {
    int acc = 0;
    for (int e = 0; e < NEXP; e++) {
      offsets[e] = acc;
      acc += atomicAdd(&counts[e], 0);  // atomic read to see L2 values
    }
    offsets[NEXP] = acc;
  }
}

// ---------- mxfp4 nibble dequant: value = fp4_table[n] * 2^(sf-127) ----------
__device__ __forceinline__ float dec_nib(uint32_t n, uint32_t sf) {
  uint32_t m = n & 7u;
  float base = ((m > 1u) && (m & 1u)) ? 1.5f : 1.0f;
  float mult = __uint_as_float(((m >> 1) + sf - 1u) << 23); // 2^((m>>1)-1 + sf-127)
  float v = (m == 0u) ? 0.0f : base * mult;
  return __uint_as_float(__float_as_uint(v) | ((n & 8u) << 28));
}

// ---------- GEMM1: h = x @ w13^T (gate+up), fused silu*up*comb -> a_buf ----------
__global__ __launch_bounds__(256) void gemm1_kernel(
    const float* __restrict__ xq, const int* __restrict__ w13,
    const int* __restrict__ w13s, const int* __restrict__ counts,
    const int* __restrict__ offsets, const int* __restrict__ lists,
    const float* __restrict__ combs, float* __restrict__ a_buf)
{
  const int e  = blockIdx.x >> 3;
  const int mt = blockIdx.x & 7;
  const int cnt = counts[e];
  const int m0 = mt << 6;
  if (m0 >= cnt) return;
  const int i0 = blockIdx.y << 6;
  const int tid = threadIdx.x;

  __shared__ __align__(16) float As[32][68];
  __shared__ __align__(16) float Bg[32][68];
  __shared__ __align__(16) float Bu[32][68];
  __shared__ int   toks[64];
  __shared__ float cmbs[64];

  if (tid < 64) {
    int m = m0 + tid;
    toks[tid] = (m < cnt) ? lists[(e<<9)+m] : -1;
    cmbs[tid] = (m < cnt) ? combs[(e<<9)+m] : 0.f;
  }
  __syncthreads();

  const int tx = tid & 15, ty = tid >> 4;
  const int am = tid >> 2, ak = (tid & 3) << 3;     // A staging: row, k-offset
  const int sel = tid >> 7;                          // 0=gate, 1=up
  const int br  = (tid >> 1) & 63;                   // B staging row (n)
  const int bc  = (tid & 1) << 3;                    // 8 packed int32 each
  const int f = i0 + br + sel * IDIM;
  const int* wrow = w13 + (size_t)(e * (2*IDIM) + f) * (DDIM/2);
  const int* srow = w13s + (size_t)(e * (2*IDIM) + f) * (DDIM/32);
  float* Bsel = sel ? &Bu[0][0] : &Bg[0][0];
  const int atok = toks[am];
  const float* arow = (atok >= 0) ? (xq + (size_t)atok * DDIM) : nullptr;

  float accg[4][4] = {}, accu[4][4] = {};

  for (int k0 = 0; k0 < DDIM; k0 += 32) {
    float4 v0 = make_float4(0,0,0,0), v1 = make_float4(0,0,0,0);
    if (arow) {
      const float* p = arow + k0 + ak;
      v0 = *(const float4*)(p);
      v1 = *(const float4*)(p + 4);
    }
    const int* bp = wrow + (k0 >> 1) + bc;
    const int4 w0 = *(const int4*)(bp);
    const int4 w1 = *(const int4*)(bp + 4);
    const uint32_t sf = (uint32_t)srow[k0 >> 5];

    __syncthreads();  // previous iter's compute done reading LDS
    As[ak+0][am] = v0.x; As[ak+1][am] = v0.y; As[ak+2][am] = v0.z; As[ak+3][am] = v0.w;
    As[ak+4][am] = v1.x; As[ak+5][am] = v1.y; As[ak+6][am] = v1.z; As[ak+7][am] = v1.w;
    {
      int wv[8] = {w0.x, w0.y, w0.z, w0.w, w1.x, w1.y, w1.z, w1.w};
#pragma unroll
      for (int j = 0; j < 8; j++) {
        uint32_t v8 = (uint32_t)wv[j];
        int kk = (bc + j) << 1;
        Bsel[kk*68 + br]     = dec_nib(v8 & 15u, sf);        // even k = low nibble
        Bsel[(kk+1)*68 + br] = dec_nib((v8 >> 4) & 15u, sf); // odd k = high nibble
      }
    }
    __syncthreads();

#pragma unroll
    for (int k = 0; k < 32; k++) {
      const float4 av = *(const float4*)&As[k][ty<<2];
      const float4 bg = *(const float4*)&Bg[k][tx<<2];
      const float4 bu = *(const float4*)&Bu[k][tx<<2];
      const float a4[4] = {av.x, av.y, av.z, av.w};
      const float g4[4] = {bg.x, bg.y, bg.z, bg.w};
      const float u4[4] = {bu.x, bu.y, bu.z, bu.w};
#pragma unroll
      for (int i = 0; i < 4; i++)
#pragma unroll
        for (int j = 0; j < 4; j++) {
          accg[i][j] = fmaf(a4[i], g4[j], accg[i][j]);
          accu[i][j] = fmaf(a4[i], u4[j], accu[i][j]);
        }
    }
  }

  const int obase = offsets[e];
#pragma unroll
  for (int i = 0; i < 4; i++) {
    int row = m0 + (ty<<2) + i;
    if (row < cnt) {
      float c = cmbs[(ty<<2) + i];
      float o[4];
#pragma unroll
      for (int j = 0; j < 4; j++) {
        float g = accg[i][j], u = accu[i][j];
        float sgm = 1.f / (1.f + expf(-g));
        o[j] = c * g * sgm * u;   // comb folded here (linear downstream)
      }
      *(float4*)&a_buf[(size_t)(obase + row) * IDIM + i0 + (tx<<2)] =
          make_float4(o[0], o[1], o[2], o[3]);
    }
  }
}

// ---------- GEMM2: out[t,:] += (comb*a) @ w2^T ----------
__global__ __launch_bounds__(256) void gemm2_kernel(
    const float* __restrict__ a_buf, const int* __restrict__ w2,
    const int* __restrict__ w2s, const int* __restrict__ counts,
    const int* __restrict__ offsets, const int* __restrict__ lists,
    float* __restrict__ out)
{
  const int e  = blockIdx.x >> 3;
  const int mt = blockIdx.x & 7;
  const int cnt = counts[e];
  const int m0 = mt << 6;
  if (m0 >= cnt) return;
  const int n0 = blockIdx.y << 6;   // d tile
  const int tid = threadIdx.x;

  __shared__ __align__(16) float As[32][68];
  __shared__ __align__(16) float Bs[32][68];
  __shared__ int toks[64];

  if (tid < 64) {
    int m = m0 + tid;
    toks[tid] = (m < cnt) ? lists[(e<<9)+m] : -1;
  }
  __syncthreads();

  const int tx = tid & 15, ty = tid >> 4;
  const int am = tid >> 2, ak = (tid & 3) << 3;
  const int br = tid >> 2, bc = (tid & 3) << 2;   // 4 int32 each
  const int obase = offsets[e];
  const int arow_i = m0 + am;
  const float* arow = (arow_i < cnt) ? (a_buf + (size_t)(obase + arow_i) * IDIM) : nullptr;
  const int d = n0 + br;
  const int* wrow = w2 + (size_t)(e * DDIM + d) * (IDIM/2);
  const int* srow = w2s + (size_t)(e * DDIM + d) * (IDIM/32);

  float acc[4][4] = {};

  for (int k0 = 0; k0 < IDIM; k0 += 32) {
    float4 v0 = make_float4(0,0,0,0), v1 = make_float4(0,0,0,0);
    if (arow) {
      const float* p = arow + k0 + ak;
      v0 = *(const float4*)(p);
      v1 = *(const float4*)(p + 4);
    }
    const int* bp = wrow + (k0 >> 1) + bc;
    const int4 w0 = *(const int4*)(bp);
    const uint32_t sf = (uint32_t)srow[k0 >> 5];

    __syncthreads();
    As[ak+0][am] = v0.x; As[ak+1][am] = v0.y; As[ak+2][am] = v0.z; As[ak+3][am] = v0.w;
    As[ak+4][am] = v1.x; As[ak+5][am] = v1.y; As[ak+6][am] = v1.z; As[ak+7][am] = v1.w;
    {
      int wv[4] = {w0.x, w0.y, w0.z, w0.w};
#pragma unroll
      for (int j = 0; j < 4; j++) {
        uint32_t v8 = (uint32_t)wv[j];
        int kk = (bc + j) << 1;
        Bs[kk][br]   = dec_nib(v8 & 15u, sf);
        Bs[kk+1][br] = dec_nib((v8 >> 4) & 15u, sf);
      }
    }
    __syncthreads();

#pragma unroll
    for (int k = 0; k < 32; k++) {
      const float4 av = *(const float4*)&As[k][ty<<2];
      const float4 bv = *(const float4*)&Bs[k][tx<<2];
      const float a4[4] = {av.x, av.y, av.z, av.w};
      const float b4[4] = {bv.x, bv.y, bv.z, bv.w};
#pragma unroll
      for (int i = 0; i < 4; i++)
#pragma unroll
        for (int j = 0; j < 4; j++)
          acc[i][j] = fmaf(a4[i], b4[j], acc[i][j]);
    }
  }

#pragma unroll
  for (int i = 0; i < 4; i++) {
    int row = m0 + (ty<<2) + i;
    if (row < cnt) {
      int tok = toks[(ty<<2) + i];
#pragma unroll
      for (int j = 0; j < 4; j++)
        atomicAdd(&out[(size_t)tok * DDIM + n0 + (tx<<2) + j], acc[i][j]);
    }
  }
}

extern "C" void kernel_launch(void* const* d_in, const int* in_sizes, int n_in,
                              void* d_out, int out_size, void* d_ws, size_t ws_size,
                              hipStream_t stream)
{
  const float* x    = (const float*)d_in[0];
  const float* tw   = (const float*)d_in[1];
  const int*   tids = (const int*)d_in[2];
  const int*   w13  = (const int*)d_in[3];
  const int*   w13s = (const int*)d_in[4];
  const int*   w2   = (const int*)d_in[5];
  const int*   w2s  = (const int*)d_in[6];
  float* out = (float*)d_out;

  char* ws = (char*)d_ws;
  float* xq      = (float*)ws;                       size_t off = (size_t)T_TOK*DDIM*4;
  int*   counts  = (int*)(ws + off);                 off += 256;
  int*   offsets = (int*)(ws + off);                 off += 256;
  int*   lists   = (int*)(ws + off);                 off += (size_t)NEXP*T_TOK*4;
  float* combs   = (float*)(ws + off);               off += (size_t)NEXP*T_TOK*4;
  float* a_buf   = (float*)(ws + off);               off += (size_t)T_TOK*TOPK*IDIM*4;
  // total ws use ~16.7 MB

  hipMemsetAsync(counts, 0, 256, stream);
  hipMemsetAsync(out, 0, (size_t)out_size * 4, stream);

  qdq_kernel<<<(T_TOK*DDIM)/256, 256, 0, stream>>>(x, xq);
  route_kernel<<<1, T_TOK, 0, stream>>>(tids, tw, counts, offsets, lists, combs);
  gemm1_kernel<<<dim3(NEXP*8, IDIM/64), 256, 0, stream>>>(
      xq, w13, w13s, counts, offsets, lists, combs, a_buf);
  gemm2_kernel<<<dim3(NEXP*8, DDIM/64), 256, 0, stream>>>(
      a_buf, w2, w2s, counts, offsets, lists, out);
}

// Round 2
// 322.371 us; speedup vs baseline: 3.4304x; 3.4304x over previous
//
#include <hip/hip_runtime.h>
#include <stdint.h>
#include <math.h>

#define T_TOK 512
#define DDIM  2048
#define IDIM  768
#define NEXP  16
#define TOPK  8
#define LDA   72   // LDS row stride (bf16 units): 64 data + 8 pad; 144 B = 16B-aligned, 2-way banks

typedef __attribute__((ext_vector_type(8))) short bf16x8;
typedef __attribute__((ext_vector_type(4))) float f32x4;

// ---------- fp8 e4m3fn RTNE quant-dequant (fp32-exact, result fits bf16) ----------
__device__ __forceinline__ float e4m3_rtne(float f) {
  uint32_t u = __float_as_uint(f);
  uint32_t sign = u & 0x80000000u;
  uint32_t a = u & 0x7FFFFFFFu;
  float fa = __uint_as_float(a);
  float out;
  if (fa >= 0.015625f) {            // normal: keep 3 mantissa bits, RTNE
    uint32_t lsb = (a >> 20) & 1u;
    a += 0x0007FFFFu + lsb;
    a &= 0xFFF00000u;
    out = __uint_as_float(a);
  } else {                          // subnormal: quantum 2^-9
    out = rintf(fa * 512.0f) * 0.001953125f;
  }
  return __uint_as_float(__float_as_uint(out) | sign);
}

__global__ void qdq_kernel(const float* __restrict__ x, ushort* __restrict__ xq) {
  int idx = blockIdx.x * 256 + threadIdx.x;
  float v = x[idx];
  float a = fabsf(v);
#pragma unroll
  for (int m = 16; m >= 1; m >>= 1)
    a = fmaxf(a, __shfl_xor(a, m, 32));
  a = fmaxf(a, 1e-4f);
  float scale = a / 448.0f;
  uint32_t b = __float_as_uint(scale);
  uint32_t ex = ((b >> 23) & 255u) + ((b & 0x7FFFFFu) ? 1u : 0u);
  ex = ex < 1u ? 1u : (ex > 254u ? 254u : ex);
  float rscale = __uint_as_float(ex << 23);
  float inv = 1.0f / rscale;
  float r = e4m3_rtne(v * inv) * rscale;       // exactly representable in bf16
  xq[idx] = (ushort)(__float_as_uint(r) >> 16);
}

// ---------- routing ----------
__global__ void route_kernel(const int* __restrict__ ids, const float* __restrict__ wts,
                             int* counts, int* offsets, int* lists, float* combs,
                             int* tpe, int* tps, int* tpn) {
  int t = threadIdx.x;  // 512 threads
  int  myid[TOPK];
  float myw[TOPK];
#pragma unroll
  for (int k = 0; k < TOPK; k++) { myid[k] = ids[t*TOPK+k]; myw[k] = wts[t*TOPK+k]; }
  int np = 0;
  for (int e = 0; e < NEXP; e++) {
    float s = 0.f; bool r = false;
#pragma unroll
    for (int k = 0; k < TOPK; k++) if (myid[k] == e) { s += myw[k]; r = true; }
    if (r) {
      int slot = atomicAdd(&counts[e], 1);
      lists[(e<<9) + slot] = t;
      combs[(e<<9) + slot] = s;
      tpe[t*TOPK + np] = e;
      tps[t*TOPK + np] = slot;
      np++;
    }
  }
  tpn[t] = np;
  __syncthreads();
  if (t == 0) {
    int acc = 0;
    for (int e = 0; e < NEXP; e++) {
      offsets[e] = acc;
      acc += atomicAdd(&counts[e], 0);
    }
    offsets[NEXP] = acc;
  }
}

// ---------- fp4 byte (2 nibbles) -> packed 2x bf16; S = (sf-1)<<1 ----------
__device__ __forceinline__ uint32_t dec2(uint32_t w8, uint32_t S) {
  uint32_t lo = w8 & 15u, hi = (w8 >> 4) & 15u;
  uint32_t mlo = lo & 7u, mhi = hi & 7u;
  uint32_t clo = (mlo < 2u) ? 0u : mlo;
  uint32_t chi = (mhi < 2u) ? 0u : mhi;
  uint32_t blo = (mlo == 0u) ? 0u : ((S + clo) << 6);
  uint32_t bhi = (mhi == 0u) ? 0u : ((S + chi) << 6);
  blo |= (lo & 8u) << 12;
  bhi |= (hi & 8u) << 12;
  return blo | (bhi << 16);
}

// ---------- GEMM1 (MFMA bf16): 256 tokens x (64 gate + 64 up), K=2048 ----------
__global__ __launch_bounds__(256,2) void gemm1_kernel(
    const ushort* __restrict__ xq, const int* __restrict__ w13,
    const int* __restrict__ w13s, const int* __restrict__ counts,
    const int* __restrict__ offsets, const int* __restrict__ lists,
    const float* __restrict__ combs, ushort* __restrict__ a_buf)
{
  const int e  = blockIdx.x;
  const int i0 = blockIdx.y << 6;
  const int m0 = blockIdx.z << 8;
  const int cnt = counts[e];
  if (m0 >= cnt) return;

  __shared__ __align__(16) ushort As[256*LDA];
  __shared__ __align__(16) ushort Bg[64*LDA];
  __shared__ __align__(16) ushort Bu[64*LDA];
  __shared__ int   toks[256];
  __shared__ float cmbs[256];

  const int tid = threadIdx.x;
  {
    int m = m0 + tid;
    bool v = m < cnt;
    toks[tid] = v ? lists[(e<<9)+m] : -1;
    cmbs[tid] = v ? combs[(e<<9)+m] : 0.f;
  }
  __syncthreads();

  // A staging map: 4 rows (ar+64p) x 16 bf16 chunk
  const int ar = tid >> 2;
  const int ac = (tid & 3) << 4;
  int atok[4];
#pragma unroll
  for (int p = 0; p < 4; p++) atok[p] = toks[ar + (p<<6)];

  // B staging map: 128 rows (64 gate + 64 up), 16 int32 per thread
  const int br = tid >> 1;
  const int bh = tid & 1;
  const int bfeat = (br < 64) ? (i0 + br) : (IDIM + i0 + (br - 64));
  const int* wrow = w13 + ((size_t)(e * 2 * IDIM) + bfeat) * (DDIM/2);
  const int* srow = w13s + ((size_t)(e * 2 * IDIM) + bfeat) * (DDIM/32);
  ushort* Brow = ((br < 64) ? Bg : Bu) + (br & 63) * LDA + (bh << 5);

  const int lane = tid & 63;
  const int wv = tid >> 6;
  const int l16 = lane & 15;
  const int q   = lane >> 4;

  f32x4 accg[4][4] = {{{0,0,0,0}}}, accu[4][4] = {{{0,0,0,0}}};

  for (int k0 = 0; k0 < DDIM; k0 += 64) {
    int4 av[4][2];
#pragma unroll
    for (int p = 0; p < 4; p++) {
      if (atok[p] >= 0) {
        const int4* src = (const int4*)(xq + (size_t)atok[p]*DDIM + k0 + ac);
        av[p][0] = src[0]; av[p][1] = src[1];
      } else {
        av[p][0] = make_int4(0,0,0,0); av[p][1] = make_int4(0,0,0,0);
      }
    }
    const int4* bp = (const int4*)(wrow + (k0 >> 1)) + (bh << 2);
    int4 wv0 = bp[0], wv1 = bp[1], wv2 = bp[2], wv3 = bp[3];
    uint32_t S = (((uint32_t)srow[(k0 >> 5) + bh]) - 1u) << 1;

    __syncthreads();   // previous iter's LDS reads complete
#pragma unroll
    for (int p = 0; p < 4; p++) {
      *(int4*)&As[(ar + (p<<6))*LDA + ac]     = av[p][0];
      *(int4*)&As[(ar + (p<<6))*LDA + ac + 8] = av[p][1];
    }
    {
      int wq[16] = {wv0.x,wv0.y,wv0.z,wv0.w, wv1.x,wv1.y,wv1.z,wv1.w,
                    wv2.x,wv2.y,wv2.z,wv2.w, wv3.x,wv3.y,wv3.z,wv3.w};
      uint32_t o[16];
#pragma unroll
      for (int j = 0; j < 16; j++) o[j] = dec2((uint32_t)wq[j], S);
#pragma unroll
      for (int c = 0; c < 4; c++)
        *(int4*)&Brow[c*8] = make_int4((int)o[4*c], (int)o[4*c+1], (int)o[4*c+2], (int)o[4*c+3]);
    }
    __syncthreads();

#pragma unroll
    for (int s = 0; s < 2; s++) {
      bf16x8 af[4];
#pragma unroll
      for (int i = 0; i < 4; i++)
        af[i] = *(const bf16x8*)&As[(wv*64 + i*16 + l16)*LDA + s*32 + q*8];
#pragma unroll
      for (int j = 0; j < 4; j++) {
        bf16x8 bg = *(const bf16x8*)&Bg[(j*16 + l16)*LDA + s*32 + q*8];
        bf16x8 bu = *(const bf16x8*)&Bu[(j*16 + l16)*LDA + s*32 + q*8];
#pragma unroll
        for (int i = 0; i < 4; i++) {
          accg[i][j] = __builtin_amdgcn_mfma_f32_16x16x32_bf16(af[i], bg, accg[i][j], 0, 0, 0);
          accu[i][j] = __builtin_amdgcn_mfma_f32_16x16x32_bf16(af[i], bu, accu[i][j], 0, 0, 0);
        }
      }
    }
  }

  const int obase = offsets[e];
#pragma unroll
  for (int i = 0; i < 4; i++) {
#pragma unroll
    for (int r = 0; r < 4; r++) {
      int mrow = wv*64 + i*16 + q*4 + r;     // C/D: row = q*4+reg, col = l16
      int gm = m0 + mrow;
      if (gm < cnt) {
        float c = cmbs[mrow];
        ushort* dst = a_buf + (size_t)(obase + gm)*IDIM + i0 + l16;
#pragma unroll
        for (int j = 0; j < 4; j++) {
          float g = accg[i][j][r], u = accu[i][j][r];
          float val = (g / (1.f + expf(-g))) * u * c;   // comb folded (linear downstream)
          uint32_t bb = __float_as_uint(val);
          bb += 0x7FFFu + ((bb >> 16) & 1u);            // RTNE to bf16
          dst[j*16] = (ushort)(bb >> 16);
        }
      }
    }
  }
}

// ---------- GEMM2 (MFMA bf16): 256 rows x 64 d-cols, K=768 ----------
__global__ __launch_bounds__(256,2) void gemm2_kernel(
    const ushort* __restrict__ a_buf, const int* __restrict__ w2,
    const int* __restrict__ w2s, const int* __restrict__ counts,
    const int* __restrict__ offsets, const int* __restrict__ lists,
    float* __restrict__ out, float* __restrict__ ye, int use_ye)
{
  const int e  = blockIdx.x;
  const int n0 = blockIdx.y << 6;
  const int m0 = blockIdx.z << 8;
  const int cnt = counts[e];
  if (m0 >= cnt) return;

  __shared__ __align__(16) ushort As[256*LDA];
  __shared__ __align__(16) ushort Bs[64*LDA];
  __shared__ int toks[256];

  const int tid = threadIdx.x;
  {
    int m = m0 + tid;
    toks[tid] = (m < cnt) ? lists[(e<<9)+m] : -1;
  }
  __syncthreads();

  const int obase = offsets[e];
  const int ar = tid >> 2;
  const int ac = (tid & 3) << 4;

  const int br = tid >> 2;           // B: 64 rows x 8 int32 per thread
  const int bq = tid & 3;
  const int* wrow = w2 + ((size_t)(e * DDIM) + n0 + br) * (IDIM/2);
  const int* srow = w2s + ((size_t)(e * DDIM) + n0 + br) * (IDIM/32);
  ushort* Brow = Bs + br * LDA + (bq << 4);

  const int lane = tid & 63;
  const int wv = tid >> 6;
  const int l16 = lane & 15;
  const int q   = lane >> 4;

  f32x4 acc[4][4] = {{{0,0,0,0}}};

  for (int k0 = 0; k0 < IDIM; k0 += 64) {
    int4 av[4][2];
#pragma unroll
    for (int p = 0; p < 4; p++) {
      int gm = m0 + ar + (p<<6);
      if (gm < cnt) {
        const int4* src = (const int4*)(a_buf + (size_t)(obase + gm)*IDIM + k0 + ac);
        av[p][0] = src[0]; av[p][1] = src[1];
      } else {
        av[p][0] = make_int4(0,0,0,0); av[p][1] = make_int4(0,0,0,0);
      }
    }
    const int4* bp = (const int4*)(wrow + (k0 >> 1)) + (bq << 1);
    int4 wv0 = bp[0], wv1 = bp[1];
    uint32_t S = (((uint32_t)srow[(k0 >> 5) + (bq >> 1)]) - 1u) << 1;

    __syncthreads();
#pragma unroll
    for (int p = 0; p < 4; p++) {
      *(int4*)&As[(ar + (p<<6))*LDA + ac]     = av[p][0];
      *(int4*)&As[(ar + (p<<6))*LDA + ac + 8] = av[p][1];
    }
    {
      int wq[8] = {wv0.x,wv0.y,wv0.z,wv0.w, wv1.x,wv1.y,wv1.z,wv1.w};
      uint32_t o[8];
#pragma unroll
      for (int j = 0; j < 8; j++) o[j] = dec2((uint32_t)wq[j], S);
      *(int4*)&Brow[0] = make_int4((int)o[0], (int)o[1], (int)o[2], (int)o[3]);
      *(int4*)&Brow[8] = make_int4((int)o[4], (int)o[5], (int)o[6], (int)o[7]);
    }
    __syncthreads();

#pragma unroll
    for (int s = 0; s < 2; s++) {
      bf16x8 af[4];
#pragma unroll
      for (int i = 0; i < 4; i++)
        af[i] = *(const bf16x8*)&As[(wv*64 + i*16 + l16)*LDA + s*32 + q*8];
#pragma unroll
      for (int j = 0; j < 4; j++) {
        bf16x8 bb = *(const bf16x8*)&Bs[(j*16 + l16)*LDA + s*32 + q*8];
#pragma unroll
        for (int i = 0; i < 4; i++)
          acc[i][j] = __builtin_amdgcn_mfma_f32_16x16x32_bf16(af[i], bb, acc[i][j], 0, 0, 0);
      }
    }
  }

#pragma unroll
  for (int i = 0; i < 4; i++) {
#pragma unroll
    for (int r = 0; r < 4; r++) {
      int mrow = wv*64 + i*16 + q*4 + r;
      int gm = m0 + mrow;
      if (gm < cnt) {
        if (use_ye) {
          float* dst = ye + (size_t)(obase + gm)*DDIM + n0 + l16;
#pragma unroll
          for (int j = 0; j < 4; j++) dst[j*16] = acc[i][j][r];
        } else {
          int tok = toks[mrow];
          float* dst = out + (size_t)tok*DDIM + n0 + l16;
#pragma unroll
          for (int j = 0; j < 4; j++) atomicAdd(&dst[j*16], acc[i][j][r]);
        }
      }
    }
  }
}

// ---------- combine: out[t,:] = sum over routed pairs of ye ----------
__global__ void combine_kernel(const float* __restrict__ ye, const int* __restrict__ offsets,
                               const int* __restrict__ tpe, const int* __restrict__ tps,
                               const int* __restrict__ tpn, float* __restrict__ out) {
  int t = blockIdx.x;
  int np = tpn[t];
  int rows[TOPK];
#pragma unroll
  for (int j = 0; j < TOPK; j++)
    rows[j] = (j < np) ? (offsets[tpe[t*TOPK+j]] + tps[t*TOPK+j]) : -1;
  for (int c = threadIdx.x; c < DDIM; c += 256) {
    float s = 0.f;
#pragma unroll
    for (int j = 0; j < TOPK; j++)
      if (rows[j] >= 0) s += ye[(size_t)rows[j]*DDIM + c];
    out[(size_t)t*DDIM + c] = s;
  }
}

extern "C" void kernel_launch(void* const* d_in, const int* in_sizes, int n_in,
                              void* d_out, int out_size, void* d_ws, size_t ws_size,
                              hipStream_t stream)
{
  const float* x    = (const float*)d_in[0];
  const float* tw   = (const float*)d_in[1];
  const int*   tids = (const int*)d_in[2];
  const int*   w13  = (const int*)d_in[3];
  const int*   w13s = (const int*)d_in[4];
  const int*   w2   = (const int*)d_in[5];
  const int*   w2s  = (const int*)d_in[6];
  float* out = (float*)d_out;

  char* ws = (char*)d_ws;
  size_t off = 0;
  ushort* xq     = (ushort*)(ws + off);  off += (size_t)T_TOK*DDIM*2;       // 2 MB
  int*   counts  = (int*)(ws + off);     off += 256;
  int*   offsets = (int*)(ws + off);     off += 256;
  int*   lists   = (int*)(ws + off);     off += (size_t)NEXP*T_TOK*4;
  float* combs   = (float*)(ws + off);   off += (size_t)NEXP*T_TOK*4;
  int*   tpe     = (int*)(ws + off);     off += (size_t)T_TOK*TOPK*4;
  int*   tps     = (int*)(ws + off);     off += (size_t)T_TOK*TOPK*4;
  int*   tpn     = (int*)(ws + off);     off += (size_t)T_TOK*4;
  ushort* a_buf  = (ushort*)(ws + off);  off += (size_t)T_TOK*TOPK*IDIM*2;  // 6 MB
  float* ye      = (float*)(ws + off);
  size_t need_ye = off + (size_t)T_TOK*TOPK*DDIM*4;                         // +32 MB
  int use_ye = (ws_size >= need_ye) ? 1 : 0;

  hipMemsetAsync(counts, 0, 256, stream);
  hipMemsetAsync(out, 0, (size_t)out_size * 4, stream);

  qdq_kernel<<<(T_TOK*DDIM)/256, 256, 0, stream>>>(x, xq);
  route_kernel<<<1, T_TOK, 0, stream>>>(tids, tw, counts, offsets, lists, combs, tpe, tps, tpn);
  gemm1_kernel<<<dim3(NEXP, IDIM/64, 2), 256, 0, stream>>>(
      xq, w13, w13s, counts, offsets, lists, combs, a_buf);
  gemm2_kernel<<<dim3(NEXP, DDIM/64, 2), 256, 0, stream>>>(
      a_buf, w2, w2s, counts, offsets, lists, out, ye, use_ye);
  if (use_ye)
    combine_kernel<<<T_TOK, 256, 0, stream>>>(ye, offsets, tpe, tps, tpn, out);
}